// Round 1
// baseline (371.617 us; speedup 1.0000x reference)
//
#include <hip/hip_runtime.h>
#include <hip/hip_bf16.h>

// Problem: b=4, c=64, n=4096 (h=w=64), head dim c/8 = 8, mlp hidden c/16 = 4.
// Workspace layout (floats):
//   Q:   [4][8][4096]   at 0         (131072)
//   K:   [4][8][4096]   at 131072    (131072)
//   V:   [4][64][4096]  at 262144    (1048576)
//   avg: [4][64]        at 1310720   (256)

#define WS_Q 0
#define WS_K 131072
#define WS_V 262144
#define WS_AVG 1310720

// ---------------------------------------------------------------------------
// Kernel A: compute Q, K, V rows. Each wg: one (b, row-group of 8, n-tile of 256).
// grid = 4 b * 10 rgroups * 16 ntiles = 640
// ---------------------------------------------------------------------------
__global__ __launch_bounds__(256) void qkv_kernel(
    const float* __restrict__ x,
    const float* __restrict__ Wq, const float* __restrict__ bq,
    const float* __restrict__ Wk, const float* __restrict__ bk,
    const float* __restrict__ Wv, const float* __restrict__ bv,
    float* __restrict__ Q, float* __restrict__ K, float* __restrict__ V)
{
    const int bx = blockIdx.x;
    const int ntile = bx & 15;
    const int rg = (bx >> 4) % 10;
    const int b = bx / 160;
    const int n = (ntile << 8) + threadIdx.x;

    const float* xb = x + b * 64 * 4096;
    const float* W;
    const float* bias;
    float* outp;
    if (rg == 0)      { W = Wq; bias = bq; outp = Q + b * 8 * 4096; }
    else if (rg == 1) { W = Wk; bias = bk; outp = K + b * 8 * 4096; }
    else {
        const int r0 = (rg - 2) * 8;
        W = Wv + r0 * 64; bias = bv + r0; outp = V + (b * 64 + r0) * 4096;
    }

    float acc[8];
#pragma unroll
    for (int j = 0; j < 8; ++j) acc[j] = bias[j];

    for (int c = 0; c < 64; ++c) {
        const float xv = xb[c * 4096 + n];
#pragma unroll
        for (int j = 0; j < 8; ++j) acc[j] += W[j * 64 + c] * xv;
    }
#pragma unroll
    for (int j = 0; j < 8; ++j) outp[j * 4096 + n] = acc[j];
}

// ---------------------------------------------------------------------------
// Kernel B: per-(b,c) mean over n. grid = 4 b * 16 groups of 4 rows = 64.
// One wave per row; coalesced reads; shuffle reduce.
// ---------------------------------------------------------------------------
__global__ __launch_bounds__(256) void avg_kernel(
    const float* __restrict__ x, float* __restrict__ avg)
{
    const int b = blockIdx.x >> 4;
    const int g = blockIdx.x & 15;
    const int w = threadIdx.x >> 6;
    const int lane = threadIdx.x & 63;
    const int c = g * 4 + w;

    const float* row = x + (b * 64 + c) * 4096;
    float s = 0.0f;
#pragma unroll 8
    for (int i = 0; i < 64; ++i) s += row[i * 64 + lane];
    for (int off = 32; off > 0; off >>= 1) s += __shfl_down(s, off);
    if (lane == 0) avg[b * 64 + c] = s * (1.0f / 4096.0f);
}

// ---------------------------------------------------------------------------
// Kernel C: attention + gate. grid = 4 b * 64 query-tiles = 256, 256 threads.
// Per key-tile of 64: stage K,V -> scores+exp into LDS -> PV accumulate.
// No max-subtraction needed: |scores| <= ~7 (bounded inputs), exp safe in fp32.
// ---------------------------------------------------------------------------
__global__ __launch_bounds__(256) void attn_kernel(
    const float* __restrict__ Qg, const float* __restrict__ Kg,
    const float* __restrict__ Vg, const float* __restrict__ avg,
    const float* __restrict__ W1, const float* __restrict__ b1,
    const float* __restrict__ W2, const float* __restrict__ b2,
    float* __restrict__ out)
{
    __shared__ float qs[8][64];
    __shared__ float ks[8][64];
    __shared__ float vs[64][68];   // +4 pad: stride 68 floats == 4 mod 32 banks
    __shared__ float es[64][68];
    __shared__ float avgs[64];
    __shared__ float gls[64];
    __shared__ float zrec[64];

    const int t = threadIdx.x;
    const int b = blockIdx.x >> 6;
    const int q0 = (blockIdx.x & 63) << 6;

    // load Q tile (512 floats, float2 per thread) + avg
    {
        const int c = t >> 5;
        const int qq = (t << 1) & 63;
        const float2 v2 = *(const float2*)&Qg[(b * 8 + c) * 4096 + q0 + qq];
        qs[c][qq] = v2.x; qs[c][qq + 1] = v2.y;
        if (t < 64) avgs[t] = avg[b * 64 + t];
    }
    __syncthreads();

    // SE gate, computed redundantly per block (tiny): threads < 64
    if (t < 64) {
        float h[4];
#pragma unroll
        for (int j = 0; j < 4; ++j) {
            float hh = b1[j];
            for (int c = 0; c < 64; ++c) hh += W1[j * 64 + c] * avgs[c];
            h[j] = fmaxf(hh, 0.0f);
        }
        float g = b2[t];
#pragma unroll
        for (int j = 0; j < 4; ++j) g += W2[t * 4 + j] * h[j];
        gls[t] = 1.0f / (1.0f + __expf(-g));
    }

    const int m1 = t >> 2;   // phase-1 key index (0..63)
    const int qp = t & 3;    // phase-1 query quarter
    const int qb = t & 15;   // phase-2 query base
    const int vb = t >> 4;   // phase-2 channel base (0..15)

    float acc[4][4];
#pragma unroll
    for (int i = 0; i < 4; ++i)
#pragma unroll
        for (int j = 0; j < 4; ++j) acc[i][j] = 0.0f;
    float zacc = 0.0f;

    for (int mt = 0; mt < 64; ++mt) {
        const int m0 = mt << 6;
        __syncthreads();   // previous tile's es/vs readers done

        // stage K tile (512 floats) and V tile (4096 floats)
        {
            const int c = t >> 5;
            const int mm = (t << 1) & 63;
            const float2 v2 = *(const float2*)&Kg[(b * 8 + c) * 4096 + m0 + mm];
            ks[c][mm] = v2.x; ks[c][mm + 1] = v2.y;

            const int v = t >> 2;
            const int ms = (t & 3) << 4;
            const float* vrow = &Vg[(b * 64 + v) * 4096 + m0 + ms];
#pragma unroll
            for (int k = 0; k < 4; ++k) {
                const float4 v4 = *(const float4*)&vrow[k * 4];
                *(float4*)&vs[v][ms + k * 4] = v4;
            }
        }
        __syncthreads();

        // phase 1: scores for (16 q) x (1 m) per thread -> exp -> es
        {
            float kreg[8];
#pragma unroll
            for (int c = 0; c < 8; ++c) kreg[c] = ks[c][m1];
#pragma unroll
            for (int i4 = 0; i4 < 4; ++i4) {
                const int qq = qp * 16 + i4 * 4;
                float s0 = 0.f, s1 = 0.f, s2 = 0.f, s3 = 0.f;
#pragma unroll
                for (int c = 0; c < 8; ++c) {
                    const float4 qv = *(const float4*)&qs[c][qq];
                    s0 += qv.x * kreg[c]; s1 += qv.y * kreg[c];
                    s2 += qv.z * kreg[c]; s3 += qv.w * kreg[c];
                }
                es[qq + 0][m1] = __expf(s0 * 0.125f);
                es[qq + 1][m1] = __expf(s1 * 0.125f);
                es[qq + 2][m1] = __expf(s2 * 0.125f);
                es[qq + 3][m1] = __expf(s3 * 0.125f);
            }
        }
        __syncthreads();

        // softmax denominator partials: wave 0 sums rows of es
        if (t < 64) {
#pragma unroll
            for (int mc = 0; mc < 16; ++mc) {
                const float4 ev = *(const float4*)&es[t][mc * 4];
                zacc += (ev.x + ev.y) + (ev.z + ev.w);
            }
        }

        // phase 2: PV accumulation, 4x4 register tile per thread
#pragma unroll
        for (int mc = 0; mc < 16; ++mc) {
            float4 ev[4], vv[4];
#pragma unroll
            for (int j = 0; j < 4; ++j) ev[j] = *(const float4*)&es[qb + 16 * j][mc * 4];
#pragma unroll
            for (int i = 0; i < 4; ++i) vv[i] = *(const float4*)&vs[vb + 16 * i][mc * 4];
#pragma unroll
            for (int i = 0; i < 4; ++i)
#pragma unroll
                for (int j = 0; j < 4; ++j) {
                    acc[i][j] += vv[i].x * ev[j].x + vv[i].y * ev[j].y
                               + vv[i].z * ev[j].z + vv[i].w * ev[j].w;
                }
        }
    }

    if (t < 64) zrec[t] = 1.0f / zacc;
    __syncthreads();

#pragma unroll
    for (int i = 0; i < 4; ++i) {
        const int v = vb + 16 * i;
        const float gv = gls[v];
#pragma unroll
        for (int j = 0; j < 4; ++j) {
            const int q = qb + 16 * j;
            out[(b * 64 + v) * 4096 + q0 + q] = acc[i][j] * zrec[q] * gv;
        }
    }
}

extern "C" void kernel_launch(void* const* d_in, const int* in_sizes, int n_in,
                              void* d_out, int out_size, void* d_ws, size_t ws_size,
                              hipStream_t stream) {
    const float* x  = (const float*)d_in[0];
    const float* Wq = (const float*)d_in[1];
    const float* bq = (const float*)d_in[2];
    const float* Wk = (const float*)d_in[3];
    const float* bk = (const float*)d_in[4];
    const float* Wv = (const float*)d_in[5];
    const float* bv = (const float*)d_in[6];
    const float* W1 = (const float*)d_in[7];
    const float* b1 = (const float*)d_in[8];
    const float* W2 = (const float*)d_in[9];
    const float* b2 = (const float*)d_in[10];

    float* ws = (float*)d_ws;
    float* Q   = ws + WS_Q;
    float* K   = ws + WS_K;
    float* V   = ws + WS_V;
    float* avg = ws + WS_AVG;
    float* out = (float*)d_out;

    qkv_kernel<<<640, 256, 0, stream>>>(x, Wq, bq, Wk, bk, Wv, bv, Q, K, V);
    avg_kernel<<<64, 256, 0, stream>>>(x, avg);
    attn_kernel<<<256, 256, 0, stream>>>(Q, K, V, avg, W1, b1, W2, b2, out);
}

// Round 2
// 178.517 us; speedup vs baseline: 2.0817x; 2.0817x over previous
//
#include <hip/hip_runtime.h>
#include <hip/hip_bf16.h>

typedef __attribute__((ext_vector_type(8))) short bf16x8;
typedef __attribute__((ext_vector_type(4))) float f32x4;
typedef __attribute__((ext_vector_type(8))) unsigned short u16x8;
typedef __attribute__((ext_vector_type(4))) unsigned short u16x4;

#define WS_Q 0
#define WS_K 131072
#define WS_V 262144
#define WS_AVG 1310720

__device__ __forceinline__ unsigned short bf_hi(float x) {
    __hip_bfloat16 h = __float2bfloat16(x);
    return *reinterpret_cast<unsigned short*>(&h);
}
__device__ __forceinline__ float bf_f(unsigned short u) {
    __hip_bfloat16 h;
    *reinterpret_cast<unsigned short*>(&h) = u;
    return __bfloat162float(h);
}

// ---------------------------------------------------------------------------
// Kernel A: compute Q, K, V rows. grid = 4 b * 10 rgroups * 16 ntiles = 640
// ---------------------------------------------------------------------------
__global__ __launch_bounds__(256) void qkv_kernel(
    const float* __restrict__ x,
    const float* __restrict__ Wq, const float* __restrict__ bq,
    const float* __restrict__ Wk, const float* __restrict__ bk,
    const float* __restrict__ Wv, const float* __restrict__ bv,
    float* __restrict__ Q, float* __restrict__ K, float* __restrict__ V)
{
    const int bx = blockIdx.x;
    const int ntile = bx & 15;
    const int rg = (bx >> 4) % 10;
    const int b = bx / 160;
    const int n = (ntile << 8) + threadIdx.x;

    const float* xb = x + b * 64 * 4096;
    const float* W;
    const float* bias;
    float* outp;
    if (rg == 0)      { W = Wq; bias = bq; outp = Q + b * 8 * 4096; }
    else if (rg == 1) { W = Wk; bias = bk; outp = K + b * 8 * 4096; }
    else {
        const int r0 = (rg - 2) * 8;
        W = Wv + r0 * 64; bias = bv + r0; outp = V + (b * 64 + r0) * 4096;
    }

    float acc[8];
#pragma unroll
    for (int j = 0; j < 8; ++j) acc[j] = bias[j];

    for (int c = 0; c < 64; ++c) {
        const float xv = xb[c * 4096 + n];
#pragma unroll
        for (int j = 0; j < 8; ++j) acc[j] += W[j * 64 + c] * xv;
    }
#pragma unroll
    for (int j = 0; j < 8; ++j) outp[j * 4096 + n] = acc[j];
}

// ---------------------------------------------------------------------------
// Kernel B: per-(b,c) mean over n. grid = 64
// ---------------------------------------------------------------------------
__global__ __launch_bounds__(256) void avg_kernel(
    const float* __restrict__ x, float* __restrict__ avg)
{
    const int b = blockIdx.x >> 4;
    const int g = blockIdx.x & 15;
    const int w = threadIdx.x >> 6;
    const int lane = threadIdx.x & 63;
    const int c = g * 4 + w;

    const float* row = x + (b * 64 + c) * 4096;
    float s = 0.0f;
#pragma unroll 8
    for (int i = 0; i < 64; ++i) s += row[i * 64 + lane];
    for (int off = 32; off > 0; off >>= 1) s += __shfl_down(s, off);
    if (lane == 0) avg[b * 64 + c] = s * (1.0f / 4096.0f);
}

// ---------------------------------------------------------------------------
// Kernel C: attention + gate. grid = 256 blocks x 512 threads.
// Block = (b, 64-query tile). 8 waves: waves 0-3 handle m in [0,2048),
// waves 4-7 handle m in [2048,4096). Per 64-m tile:
//   stage: K fp32 + V(hi/lo bf16) -> LDS;  phase1: fp32 scores -> exp ->
//   P(hi/lo bf16) -> LDS;  phase2: PV via mfma_f32_16x16x32_bf16 with
//   3-product hi/lo compensation (error ~2^-17).
// Planes stored [row][m] stride 72 ushorts (144B = 9*16B): b128-aligned,
// bank-balanced for both staging writes and fragment reads.
// ---------------------------------------------------------------------------
__global__ __launch_bounds__(512) void attn_kernel(
    const float* __restrict__ Qg, const float* __restrict__ Kg,
    const float* __restrict__ Vg, const float* __restrict__ avg,
    const float* __restrict__ W1, const float* __restrict__ b1,
    const float* __restrict__ W2, const float* __restrict__ b2,
    float* __restrict__ out)
{
    __shared__ float ks[2][8][64];
    __shared__ unsigned short Vh[2][64][72];
    __shared__ unsigned short Vl[2][64][72];
    __shared__ unsigned short Ph[2][64][72];
    __shared__ unsigned short Pl[2][64][72];
    __shared__ float cpart[4][16][68];
    __shared__ float zls[2][64];
    __shared__ float zrec[64];
    __shared__ float gls[64];
    __shared__ float avgs[64];

    const int t   = threadIdx.x;
    const int h   = t >> 8;          // m-half 0/1
    const int tt  = t & 255;         // thread-in-half
    const int w   = t >> 6;          // wave 0..7
    const int ws  = w & 3;           // v-stripe (16 rows) within half
    const int l   = t & 63;          // lane

    const int b  = blockIdx.x >> 6;
    const int q0 = (blockIdx.x & 63) << 6;
    const int mbase = h << 11;       // 0 or 2048

    const int p1q = tt & 15;         // phase1: q = p1q + 16*i
    const int p1m = tt >> 4;         // phase1: m-quad (0..15)

    const int sv = tt >> 2;          // stage: V row
    const int sm = (tt & 3) << 4;    // stage: V col base (16 elems)
    const int kc = tt >> 5;          // stage: K row
    const int km = (tt & 31) << 1;   // stage: K col base (2 elems)

    if (t < 64) avgs[t] = avg[b * 64 + t];
    if (t < 128) zls[t >> 6][t & 63] = 0.0f;

    // Q into registers: qreg[c][i] = Q[b][c][q0 + p1q + 16 i]
    float qreg[8][4];
#pragma unroll
    for (int c = 0; c < 8; ++c)
#pragma unroll
        for (int i = 0; i < 4; ++i)
            qreg[c][i] = Qg[(b * 8 + c) * 4096 + q0 + p1q + 16 * i];

    // prefetch tile 0
    float4 vpre[4];
    float2 kpre;
    {
        const float* vrow = &Vg[(b * 64 + sv) * 4096 + mbase + sm];
#pragma unroll
        for (int g = 0; g < 4; ++g) vpre[g] = *(const float4*)&vrow[4 * g];
        kpre = *(const float2*)&Kg[(b * 8 + kc) * 4096 + mbase + km];
    }

    __syncthreads();

    // SE gate (tiny, redundant per block)
    if (t < 64) {
        float hreg[4];
#pragma unroll
        for (int j = 0; j < 4; ++j) {
            float hh = b1[j];
            for (int c = 0; c < 64; ++c) hh += W1[j * 64 + c] * avgs[c];
            hreg[j] = fmaxf(hh, 0.0f);
        }
        float g = b2[t];
#pragma unroll
        for (int j = 0; j < 4; ++j) g += W2[t * 4 + j] * hreg[j];
        gls[t] = 1.0f / (1.0f + __expf(-g));
    }

    f32x4 acc[4];
#pragma unroll
    for (int qt = 0; qt < 4; ++qt)
#pragma unroll
        for (int r = 0; r < 4; ++r) acc[qt][r] = 0.0f;
    float zreg[4] = {0.f, 0.f, 0.f, 0.f};

    for (int mt = 0; mt < 32; ++mt) {
        __syncthreads();               // prev phase2 readers done

        // ---- stage: K fp32 + V hi/lo bf16 ----
        *(float2*)&ks[h][kc][km] = kpre;
        {
            unsigned short hbuf[16], lbuf[16];
#pragma unroll
            for (int g = 0; g < 4; ++g) {
                const float4 v4 = vpre[g];
                const float vv[4] = {v4.x, v4.y, v4.z, v4.w};
#pragma unroll
                for (int k = 0; k < 4; ++k) {
                    const unsigned short hi = bf_hi(vv[k]);
                    hbuf[4 * g + k] = hi;
                    lbuf[4 * g + k] = bf_hi(vv[k] - bf_f(hi));
                }
            }
            *(u16x8*)&Vh[h][sv][sm]     = *(u16x8*)&hbuf[0];
            *(u16x8*)&Vh[h][sv][sm + 8] = *(u16x8*)&hbuf[8];
            *(u16x8*)&Vl[h][sv][sm]     = *(u16x8*)&lbuf[0];
            *(u16x8*)&Vl[h][sv][sm + 8] = *(u16x8*)&lbuf[8];
        }

        // ---- prefetch next tile (latency hidden under phases) ----
        {
            const int mtn = (mt < 31) ? mt + 1 : mt;
            const float* vrow = &Vg[(b * 64 + sv) * 4096 + mbase + mtn * 64 + sm];
#pragma unroll
            for (int g = 0; g < 4; ++g) vpre[g] = *(const float4*)&vrow[4 * g];
            kpre = *(const float2*)&Kg[(b * 8 + kc) * 4096 + mbase + mtn * 64 + km];
        }

        __syncthreads();               // stage visible

        // ---- phase 1: fp32 scores -> exp -> P hi/lo ----
        {
            float4 kv[8];
#pragma unroll
            for (int c = 0; c < 8; ++c) kv[c] = *(const float4*)&ks[h][c][4 * p1m];
#pragma unroll
            for (int i = 0; i < 4; ++i) {
                float s0 = 0.f, s1 = 0.f, s2 = 0.f, s3 = 0.f;
#pragma unroll
                for (int c = 0; c < 8; ++c) {
                    const float qc = qreg[c][i];
                    s0 += qc * kv[c].x; s1 += qc * kv[c].y;
                    s2 += qc * kv[c].z; s3 += qc * kv[c].w;
                }
                float p[4] = {__expf(s0 * 0.125f), __expf(s1 * 0.125f),
                              __expf(s2 * 0.125f), __expf(s3 * 0.125f)};
                zreg[i] += (p[0] + p[1]) + (p[2] + p[3]);
                unsigned short hb[4], lb[4];
#pragma unroll
                for (int k = 0; k < 4; ++k) {
                    hb[k] = bf_hi(p[k]);
                    lb[k] = bf_hi(p[k] - bf_f(hb[k]));
                }
                *(u16x4*)&Ph[h][p1q + 16 * i][4 * p1m] = *(u16x4*)&hb[0];
                *(u16x4*)&Pl[h][p1q + 16 * i][4 * p1m] = *(u16x4*)&lb[0];
            }
        }

        __syncthreads();               // P visible

        // ---- phase 2: PV via MFMA, 3-product hi/lo ----
        {
            const int arow = ws * 16 + (l & 15);
            const int kofs = 8 * (l >> 4);
#pragma unroll
            for (int kcb = 0; kcb < 2; ++kcb) {
                const int mofs = kcb * 32 + kofs;
                const bf16x8 ah = *(const bf16x8*)&Vh[h][arow][mofs];
                const bf16x8 al = *(const bf16x8*)&Vl[h][arow][mofs];
#pragma unroll
                for (int qt = 0; qt < 4; ++qt) {
                    const bf16x8 bh = *(const bf16x8*)&Ph[h][qt * 16 + (l & 15)][mofs];
                    const bf16x8 bl = *(const bf16x8*)&Pl[h][qt * 16 + (l & 15)][mofs];
                    acc[qt] = __builtin_amdgcn_mfma_f32_16x16x32_bf16(ah, bh, acc[qt], 0, 0, 0);
                    acc[qt] = __builtin_amdgcn_mfma_f32_16x16x32_bf16(ah, bl, acc[qt], 0, 0, 0);
                    acc[qt] = __builtin_amdgcn_mfma_f32_16x16x32_bf16(al, bh, acc[qt], 0, 0, 0);
                }
            }
        }
    }

    // ---- softmax denominator reduce ----
#pragma unroll
    for (int i = 0; i < 4; ++i) atomicAdd(&zls[h][p1q + 16 * i], zreg[i]);
    __syncthreads();
    if (t < 64) zrec[t] = 1.0f / (zls[0][t] + zls[1][t]);

    // ---- combine halves + epilogue ----
    if (h == 1) {
#pragma unroll
        for (int qt = 0; qt < 4; ++qt)
#pragma unroll
            for (int r = 0; r < 4; ++r)
                cpart[ws][(l >> 4) * 4 + r][qt * 16 + (l & 15)] = acc[qt][r];
    }
    __syncthreads();

    if (h == 0) {
#pragma unroll
        for (int qt = 0; qt < 4; ++qt) {
            const int qglob = qt * 16 + (l & 15);
            const float rz = zrec[qglob];
#pragma unroll
            for (int r = 0; r < 4; ++r) {
                const int rowl = (l >> 4) * 4 + r;
                const int vglob = ws * 16 + rowl;
                const float v = acc[qt][r] + cpart[ws][rowl][qglob];
                out[(b * 64 + vglob) * 4096 + q0 + qglob] = v * rz * gls[vglob];
            }
        }
    }
}

extern "C" void kernel_launch(void* const* d_in, const int* in_sizes, int n_in,
                              void* d_out, int out_size, void* d_ws, size_t ws_size,
                              hipStream_t stream) {
    const float* x  = (const float*)d_in[0];
    const float* Wq = (const float*)d_in[1];
    const float* bq = (const float*)d_in[2];
    const float* Wk = (const float*)d_in[3];
    const float* bk = (const float*)d_in[4];
    const float* Wv = (const float*)d_in[5];
    const float* bv = (const float*)d_in[6];
    const float* W1 = (const float*)d_in[7];
    const float* b1 = (const float*)d_in[8];
    const float* W2 = (const float*)d_in[9];
    const float* b2 = (const float*)d_in[10];

    float* ws = (float*)d_ws;
    float* Q   = ws + WS_Q;
    float* K   = ws + WS_K;
    float* V   = ws + WS_V;
    float* avg = ws + WS_AVG;
    float* out = (float*)d_out;

    qkv_kernel<<<640, 256, 0, stream>>>(x, Wq, bq, Wk, bk, Wv, bv, Q, K, V);
    avg_kernel<<<64, 256, 0, stream>>>(x, avg);
    attn_kernel<<<256, 512, 0, stream>>>(Q, K, V, avg, W1, b1, W2, b2, out);
}

// Round 3
// 115.656 us; speedup vs baseline: 3.2131x; 1.5435x over previous
//
#include <hip/hip_runtime.h>
#include <hip/hip_bf16.h>

typedef __attribute__((ext_vector_type(8))) short bf16x8;
typedef __attribute__((ext_vector_type(4))) float f32x4;
typedef __attribute__((ext_vector_type(4))) unsigned short u16x4;
typedef __attribute__((ext_vector_type(8))) unsigned short u16x8;

// ws layout (ushort units):
//   Qb [4][4096][8]  @ 0        bf16, pre-scaled by 0.125, [n][c] fragment layout
//   Kb [4][4096][8]  @ 131072   bf16, [m][c]
//   Vb [4][64][4096] @ 262144   bf16, [v][n]
//   avg floats (256) @ ushort offset 1310720
#define WS_QB 0
#define WS_KB 131072
#define WS_VB 262144
#define WS_AVG_U 1310720

__device__ __forceinline__ unsigned short bf_hi(float x) {
    __hip_bfloat16 h = __float2bfloat16(x);
    return *reinterpret_cast<unsigned short*>(&h);
}

// ---------------------------------------------------------------------------
// Kernel A: Q,K,V projections -> bf16 workspace. grid = 640 x 256
// ---------------------------------------------------------------------------
__global__ __launch_bounds__(256) void qkv_kernel(
    const float* __restrict__ x,
    const float* __restrict__ Wq, const float* __restrict__ bq,
    const float* __restrict__ Wk, const float* __restrict__ bk,
    const float* __restrict__ Wv, const float* __restrict__ bv,
    unsigned short* __restrict__ Qb, unsigned short* __restrict__ Kb,
    unsigned short* __restrict__ Vb)
{
    const int bx = blockIdx.x;
    const int ntile = bx & 15;
    const int rg = (bx >> 4) % 10;
    const int b = bx / 160;
    const int n = (ntile << 8) + threadIdx.x;
    const float* xb = x + b * 262144;

    const float* W; const float* bias;
    if (rg == 0)      { W = Wq; bias = bq; }
    else if (rg == 1) { W = Wk; bias = bk; }
    else              { W = Wv + (rg - 2) * 8 * 64; bias = bv + (rg - 2) * 8; }

    float acc[8];
#pragma unroll
    for (int j = 0; j < 8; ++j) acc[j] = bias[j];

#pragma unroll 8
    for (int c = 0; c < 64; ++c) {
        const float xv = xb[c * 4096 + n];
#pragma unroll
        for (int j = 0; j < 8; ++j) acc[j] += W[j * 64 + c] * xv;
    }

    if (rg == 0) {
        unsigned short tmp[8];
#pragma unroll
        for (int j = 0; j < 8; ++j) tmp[j] = bf_hi(acc[j] * 0.125f);
        *(u16x8*)&Qb[(b * 4096 + n) * 8] = *(const u16x8*)tmp;
    } else if (rg == 1) {
        unsigned short tmp[8];
#pragma unroll
        for (int j = 0; j < 8; ++j) tmp[j] = bf_hi(acc[j]);
        *(u16x8*)&Kb[(b * 4096 + n) * 8] = *(const u16x8*)tmp;
    } else {
        const int r0 = (rg - 2) * 8;
#pragma unroll
        for (int j = 0; j < 8; ++j) Vb[(b * 64 + r0 + j) * 4096 + n] = bf_hi(acc[j]);
    }
}

// ---------------------------------------------------------------------------
// Kernel B: per-(b,c) mean. grid = 256 (one block per row)
// ---------------------------------------------------------------------------
__global__ __launch_bounds__(256) void avg_kernel(
    const float* __restrict__ x, float* __restrict__ avg)
{
    const int bc = blockIdx.x;
    const int t = threadIdx.x;
    const float* row = x + bc * 4096;
    float s = 0.0f;
#pragma unroll
    for (int k = 0; k < 4; ++k) {
        const float4 v = *(const float4*)&row[t * 16 + k * 4];
        s += (v.x + v.y) + (v.z + v.w);
    }
    for (int off = 32; off > 0; off >>= 1) s += __shfl_down(s, off);
    __shared__ float wsum[4];
    if ((t & 63) == 0) wsum[t >> 6] = s;
    __syncthreads();
    if (t == 0) avg[bc] = (wsum[0] + wsum[1] + wsum[2] + wsum[3]) * (1.0f / 4096.0f);
}

// ---------------------------------------------------------------------------
// Kernel C: attention + gate. grid = 256 x 512. Waves 0-3: m in [0,2048),
// waves 4-7: m in [2048,4096). Per 64-m tile (2 barriers, V double-buffered):
//   phase1: QK^T via 1 MFMA (k-groups 1-3 zero) -> exp in D-regs -> P bf16 LDS
//   phase2: PV via 8 mfma_f32_16x16x32_bf16. V/P XOR-swizzled (T2).
// ---------------------------------------------------------------------------
__global__ __launch_bounds__(512) void attn_kernel(
    const unsigned short* __restrict__ Qb, const unsigned short* __restrict__ Kb,
    const unsigned short* __restrict__ Vb, const float* __restrict__ avg,
    const float* __restrict__ W1, const float* __restrict__ b1,
    const float* __restrict__ W2, const float* __restrict__ b2,
    float* __restrict__ out)
{
    __shared__ __align__(16) unsigned short smem[24576]; // Vs[2h][2buf][64][64] | Ps[2h][64][64]
    __shared__ float zls[64], zrec[64], gls[64], avgs[64];

    const int t = threadIdx.x;
    const int h = t >> 8;
    const int tt = t & 255;
    const int ws_ = (t >> 6) & 3;
    const int l = t & 63;
    const int g = l >> 4;
    const int l15 = l & 15;

    const int b = blockIdx.x >> 6;
    const int q0 = (blockIdx.x & 63) << 6;
    const int mbase = h << 11;

    unsigned short* VsH = smem + h * 8192;          // [buf][64][64]
    unsigned short* PsH = smem + 16384 + h * 4096;  // [64][64]

    if (t < 64) { avgs[t] = avg[b * 64 + t]; zls[t] = 0.0f; }

    // Q fragments (B operand): col=q=l15, k-group 0 = channels, groups 1-3 zero
    bf16x8 zf = {};
    bf16x8 qf[4];
#pragma unroll
    for (int qt = 0; qt < 4; ++qt) {
        bf16x8 v = *(const bf16x8*)&Qb[(b * 4096 + q0 + qt * 16 + l15) * 8];
        qf[qt] = (g == 0) ? v : zf;
    }

    // staging geometry: 256 threads/half stage 64x64 bf16 (32B each)
    const int srow = tt >> 2;
    const int scol = (tt & 3) * 16;                 // ushort col base
    const int ssw = (srow & 7) << 3;
    const unsigned short* vsrc = &Vb[(b * 64 + srow) * 4096 + mbase];

    // prologue: stage V_0 into buf 0
    {
        u16x8 a = *(const u16x8*)&vsrc[scol];
        u16x8 c = *(const u16x8*)&vsrc[scol + 8];
        *(u16x8*)&VsH[srow * 64 + (scol ^ ssw)] = a;
        *(u16x8*)&VsH[srow * 64 + ((scol + 8) ^ ssw)] = c;
    }
    // K fragment prefetch, tile 0 (A operand rows = m)
    const int mrow = ws_ * 16 + l15;
    bf16x8 kf_next;
    {
        bf16x8 kv = *(const bf16x8*)&Kb[(b * 4096 + mbase + mrow) * 8];
        kf_next = (g == 0) ? kv : zf;
    }

    f32x4 acc[4];
#pragma unroll
    for (int qt = 0; qt < 4; ++qt)
#pragma unroll
        for (int r = 0; r < 4; ++r) acc[qt][r] = 0.0f;
    float zreg[4] = {0.f, 0.f, 0.f, 0.f};
    const int vswz = ((ws_ * 16 + l15) & 7) << 3;

    for (int i = 0; i < 32; ++i) {
        __syncthreads();   // bar A: prev phase2 done reading Ps / Vs[(i-1)&1]

        const int inx = (i < 31) ? i + 1 : 31;
        // issue V_{i+1} global loads (drain at bar B, covered by phase1)
        u16x8 va = *(const u16x8*)&vsrc[inx * 64 + scol];
        u16x8 vb2 = *(const u16x8*)&vsrc[inx * 64 + scol + 8];

        // phase 1: scores via MFMA -> exp -> P
        bf16x8 kf = kf_next;
        {
            bf16x8 kv = *(const bf16x8*)&Kb[(b * 4096 + mbase + inx * 64 + mrow) * 8];
            kf_next = (g == 0) ? kv : zf;
        }
        f32x4 dz;
#pragma unroll
        for (int r = 0; r < 4; ++r) dz[r] = 0.0f;
#pragma unroll
        for (int qt = 0; qt < 4; ++qt) {
            f32x4 d = __builtin_amdgcn_mfma_f32_16x16x32_bf16(kf, qf[qt], dz, 0, 0, 0);
            float p[4];
#pragma unroll
            for (int r = 0; r < 4; ++r) p[r] = __expf(d[r]);
            zreg[qt] += (p[0] + p[1]) + (p[2] + p[3]);
            u16x4 pw;
#pragma unroll
            for (int r = 0; r < 4; ++r) pw[r] = bf_hi(p[r]);
            const int q = qt * 16 + l15;
            const int col = ws_ * 16 + g * 4;
            *(u16x4*)&PsH[q * 64 + (col ^ ((q & 7) << 3))] = pw;
        }

        __syncthreads();   // bar B: Ps + (prologue/stage) V_i visible

        // stage V_{i+1} -> buf (i+1)&1
        {
            const int base = ((i + 1) & 1) * 4096 + srow * 64;
            *(u16x8*)&VsH[base + (scol ^ ssw)] = va;
            *(u16x8*)&VsH[base + ((scol + 8) ^ ssw)] = vb2;
        }

        // phase 2: PV MFMAs from Vs[i&1], Ps
        {
            const int vbase = (i & 1) * 4096 + (ws_ * 16 + l15) * 64;
#pragma unroll
            for (int kcb = 0; kcb < 2; ++kcb) {
                const int colA = kcb * 32 + g * 8;
                const bf16x8 af = *(const bf16x8*)&VsH[vbase + (colA ^ vswz)];
#pragma unroll
                for (int qt = 0; qt < 4; ++qt) {
                    const int q = qt * 16 + l15;
                    const bf16x8 bfr = *(const bf16x8*)&PsH[q * 64 + (colA ^ ((q & 7) << 3))];
                    acc[qt] = __builtin_amdgcn_mfma_f32_16x16x32_bf16(af, bfr, acc[qt], 0, 0, 0);
                }
            }
        }
    }

    __syncthreads();   // E1: loop done

    // z reduction: combine lane groups, then atomic per q
#pragma unroll
    for (int qt = 0; qt < 4; ++qt) {
        float z = zreg[qt];
        z += __shfl_xor(z, 16);
        z += __shfl_xor(z, 32);
        if (g == 0) atomicAdd(&zls[qt * 16 + l15], z);
    }
    // SE gate (tiny, after loop so it doesn't stall the pipeline)
    if (t < 64) {
        float hreg[4];
#pragma unroll
        for (int j = 0; j < 4; ++j) {
            float hh = b1[j];
            for (int c = 0; c < 64; ++c) hh += W1[j * 64 + c] * avgs[c];
            hreg[j] = fmaxf(hh, 0.0f);
        }
        float gg = b2[t];
#pragma unroll
        for (int j = 0; j < 4; ++j) gg += W2[t * 4 + j] * hreg[j];
        gls[t] = 1.0f / (1.0f + __expf(-gg));
    }
    __syncthreads();   // E2: zls complete, gate done

    if (t < 64) zrec[t] = 1.0f / zls[t];
    float* cpart = (float*)smem;   // [64 v][68] fp32, aliased over Vs (dead)
    if (h == 1) {
#pragma unroll
        for (int qt = 0; qt < 4; ++qt)
#pragma unroll
            for (int r = 0; r < 4; ++r)
                cpart[(ws_ * 16 + g * 4 + r) * 68 + qt * 16 + l15] = acc[qt][r];
    }
    __syncthreads();   // E3

    if (h == 0) {
#pragma unroll
        for (int qt = 0; qt < 4; ++qt) {
            const int q = qt * 16 + l15;
            const float rz = zrec[q];
#pragma unroll
            for (int r = 0; r < 4; ++r) {
                const int v = ws_ * 16 + g * 4 + r;
                const float val = acc[qt][r] + cpart[v * 68 + q];
                out[(b * 64 + v) * 4096 + q0 + q] = val * rz * gls[v];
            }
        }
    }
}

extern "C" void kernel_launch(void* const* d_in, const int* in_sizes, int n_in,
                              void* d_out, int out_size, void* d_ws, size_t ws_size,
                              hipStream_t stream) {
    const float* x  = (const float*)d_in[0];
    const float* Wq = (const float*)d_in[1];
    const float* bq = (const float*)d_in[2];
    const float* Wk = (const float*)d_in[3];
    const float* bk = (const float*)d_in[4];
    const float* Wv = (const float*)d_in[5];
    const float* bv = (const float*)d_in[6];
    const float* W1 = (const float*)d_in[7];
    const float* b1 = (const float*)d_in[8];
    const float* W2 = (const float*)d_in[9];
    const float* b2 = (const float*)d_in[10];

    unsigned short* wsu = (unsigned short*)d_ws;
    unsigned short* Qb = wsu + WS_QB;
    unsigned short* Kb = wsu + WS_KB;
    unsigned short* Vb = wsu + WS_VB;
    float* avg = (float*)(wsu + WS_AVG_U);
    float* out = (float*)d_out;

    qkv_kernel<<<640, 256, 0, stream>>>(x, Wq, bq, Wk, bk, Wv, bv, Qb, Kb, Vb);
    avg_kernel<<<256, 256, 0, stream>>>(x, avg);
    attn_kernel<<<256, 512, 0, stream>>>(Qb, Kb, Vb, avg, W1, b1, W2, b2, out);
}